// Round 8
// baseline (46.027 us; speedup 1.0000x reference)
//
#include <hip/hip_runtime.h>

// SurvivalNLLLoss: hazard [T=128, B=262144] fp32, event_times [B] int,
// censored [B] int(bool). Output: scalar mean loss (fp32).
//
// Per column b: t = min(event[b], T-1), S_t = sum_{i<=t} log(1-h_i)
//   loss = -S_t + (censored ? 0 : log(1-h_t) - log(h_t))
//
// Round-8: single fused kernel. Each block computes its (T-chunk x 1024-col)
// partial, scales by 1/B, and device-scope atomicAdd's it into d_out[0]
// (zeroed per call via hipMemsetAsync). NO __threadfence — that was the
// R3/R4 poison (buffer_wbl2 whole-L2 writeback per block, ~100us). Device-
// scope float atomics execute at the coherence point, bypassing the
// non-coherent per-XCD L2s, so no fence is needed. 2048 atomics spread over
// the kernel lifetime -> negligible contention. FP-atomic order wobble
// ~1e-4 absolute on the mean, far inside the 1.24 threshold.
// Pass-1 body identical to R7 (NCHUNK=8, nt float4 loads, log2-domain).

typedef float floatx4 __attribute__((ext_vector_type(4)));

static constexpr int T_DIM  = 128;
static constexpr int NCHUNK = 8;
static constexpr int ROWS   = T_DIM / NCHUNK;   // 16
static constexpr float EPS_F = 1e-7f;
static constexpr float LN2   = 0.6931471805599453f;

__global__ __launch_bounds__(256) void surv_fused(
    const float* __restrict__ hazard,
    const int* __restrict__ event_times,
    const int* __restrict__ censored,
    float* __restrict__ out,
    int B, float inv_count)
{
    const int tc   = blockIdx.x % NCHUNK;          // T-chunk index
    const int cb   = blockIdx.x / NCHUNK;          // column-block index
    const int col0 = (cb * 256 + threadIdx.x) * 4;
    const int r0   = tc * ROWS;

    float local = 0.0f;
    if (col0 + 3 < B) {
        const int4 tt = *reinterpret_cast<const int4*>(event_times + col0);
        int t[4];
        t[0] = min(tt.x, T_DIM - 1); t[1] = min(tt.y, T_DIM - 1);
        t[2] = min(tt.z, T_DIM - 1); t[3] = min(tt.w, T_DIM - 1);

        float S2[4]   = {0.0f, 0.0f, 0.0f, 0.0f};  // sum log2(1-h), i<=t
        float hsel[4] = {0.5f, 0.5f, 0.5f, 0.5f};  // clamped h at row t

        const float* p = hazard + (size_t)r0 * (size_t)B + col0;

        #pragma unroll 8
        for (int i = 0; i < ROWS; ++i) {
            const floatx4 h4 = __builtin_nontemporal_load(
                reinterpret_cast<const floatx4*>(p + (size_t)i * (size_t)B));
            const int row = r0 + i;
            #pragma unroll
            for (int c = 0; c < 4; ++c) {
                const float h   = fminf(fmaxf(h4[c], EPS_F), 1.0f - EPS_F);
                const float ls2 = __log2f(1.0f - h);
                S2[c]  += (row <= t[c]) ? ls2 : 0.0f;
                hsel[c] = (row == t[c]) ? h   : hsel[c];
            }
        }

        const int4 cc = *reinterpret_cast<const int4*>(censored + col0);
        const int cens[4] = {cc.x, cc.y, cc.z, cc.w};
        #pragma unroll
        for (int c = 0; c < 4; ++c) {
            const bool has_t = (unsigned)(t[c] - r0) < (unsigned)ROWS;
            const float term = __log2f(1.0f - hsel[c]) - __log2f(hsel[c]);
            float contrib = -S2[c];
            if (has_t && (cens[c] == 0)) contrib += term;
            local += contrib;
        }
        local *= LN2;
    }

    // ---- wave (64-lane) + block reduction ----
    #pragma unroll
    for (int off = 32; off > 0; off >>= 1)
        local += __shfl_down(local, off);

    __shared__ float smem[4];
    const int lane = threadIdx.x & 63;
    const int wid  = threadIdx.x >> 6;
    if (lane == 0) smem[wid] = local;
    __syncthreads();

    // one device-scope atomic per block, pre-scaled by 1/B
    if (threadIdx.x == 0)
        atomicAdd(out, (smem[0] + smem[1] + smem[2] + smem[3]) * inv_count);
}

extern "C" void kernel_launch(void* const* d_in, const int* in_sizes, int n_in,
                              void* d_out, int out_size, void* d_ws, size_t ws_size,
                              hipStream_t stream)
{
    const float* hazard      = (const float*)d_in[0];
    const int*   event_times = (const int*)d_in[1];
    const int*   censored    = (const int*)d_in[2];
    float*       out         = (float*)d_out;

    const int B = in_sizes[1];              // 262144
    (void)n_in; (void)out_size; (void)d_ws; (void)ws_size;

    const int threads = 256;
    const int cols_per_block = threads * 4;                           // 1024
    const int col_blocks = (B + cols_per_block - 1) / cols_per_block; // 256
    const int nblocks = col_blocks * NCHUNK;                          // 2048

    hipMemsetAsync(out, 0, sizeof(float), stream);

    surv_fused<<<nblocks, threads, 0, stream>>>(hazard, event_times, censored,
                                                out, B, 1.0f / (float)B);
}

// Round 9
// 30.118 us; speedup vs baseline: 1.5282x; 1.5282x over previous
//
#include <hip/hip_runtime.h>

// SurvivalNLLLoss: hazard [T=128, B=262144] fp32, event_times [B] int,
// censored [B] int(bool). Output: scalar mean loss (fp32).
//
// Per column b: t = min(event[b], T-1), S_t = sum_{i<=t} log(1-h_i)
//   loss = -S_t + (censored ? 0 : log(1-h_t) - log(h_t))
//
// Round-9: back to the proven two-kernel skeleton (R8's fused atomicAdd
// paid a ~16us same-address atomic tail: 2048 co-resident blocks finish
// together -> burst of serialized ~7.8ns atomics; a last-block counter
// would hit the identical hotspot; __threadfence = wbl2 = ~100us, R3/R4).
// Probe this round: per-thread MLP. 8 cols/thread = 2x dwordx4 per row,
// ROWS=16 fully unrolled -> up to 32 loads clusterable per wave. Plain
// (cached) loads so warm replays can be L3-served. If pass-1 stays at
// ~5.4 TB/s, the read path is pinned and 30us is the structural optimum.

static constexpr int T_DIM  = 128;
static constexpr int NCHUNK = 8;
static constexpr int ROWS   = T_DIM / NCHUNK;   // 16
static constexpr int CPT    = 8;                // cols per thread
static constexpr float EPS_F = 1e-7f;
static constexpr float LN2   = 0.6931471805599453f;

// ---------------- pass 1: per-block partial sums -----------------------------
__global__ __launch_bounds__(256) void surv_partial(
    const float* __restrict__ hazard,
    const int* __restrict__ event_times,
    const int* __restrict__ censored,
    float* __restrict__ partials, int B)
{
    const int tc   = blockIdx.x % NCHUNK;          // T-chunk index
    const int cb   = blockIdx.x / NCHUNK;          // column-block index
    const int col0 = (cb * 256 + threadIdx.x) * CPT;
    const int r0   = tc * ROWS;

    float local = 0.0f;
    if (col0 + CPT - 1 < B) {
        int t[CPT];
        #pragma unroll
        for (int q = 0; q < 2; ++q) {
            const int4 tt = *reinterpret_cast<const int4*>(event_times + col0 + 4*q);
            t[4*q+0] = min(tt.x, T_DIM - 1); t[4*q+1] = min(tt.y, T_DIM - 1);
            t[4*q+2] = min(tt.z, T_DIM - 1); t[4*q+3] = min(tt.w, T_DIM - 1);
        }

        float S2[CPT], hsel[CPT];
        #pragma unroll
        for (int c = 0; c < CPT; ++c) { S2[c] = 0.0f; hsel[c] = 0.5f; }

        const float* p = hazard + (size_t)r0 * (size_t)B + col0;

        #pragma unroll
        for (int i = 0; i < ROWS; ++i) {
            const float4 a = *reinterpret_cast<const float4*>(p + (size_t)i * (size_t)B);
            const float4 b = *reinterpret_cast<const float4*>(p + (size_t)i * (size_t)B + 4);
            const int row = r0 + i;
            const float hv[CPT] = {a.x, a.y, a.z, a.w, b.x, b.y, b.z, b.w};
            #pragma unroll
            for (int c = 0; c < CPT; ++c) {
                const float h   = fminf(fmaxf(hv[c], EPS_F), 1.0f - EPS_F);
                const float ls2 = __log2f(1.0f - h);
                S2[c]  += (row <= t[c]) ? ls2 : 0.0f;
                hsel[c] = (row == t[c]) ? h   : hsel[c];
            }
        }

        int cens[CPT];
        #pragma unroll
        for (int q = 0; q < 2; ++q) {
            const int4 cc = *reinterpret_cast<const int4*>(censored + col0 + 4*q);
            cens[4*q+0] = cc.x; cens[4*q+1] = cc.y;
            cens[4*q+2] = cc.z; cens[4*q+3] = cc.w;
        }
        #pragma unroll
        for (int c = 0; c < CPT; ++c) {
            const bool has_t = (unsigned)(t[c] - r0) < (unsigned)ROWS;
            const float term = __log2f(1.0f - hsel[c]) - __log2f(hsel[c]);
            float contrib = -S2[c];
            if (has_t && (cens[c] == 0)) contrib += term;
            local += contrib;
        }
        local *= LN2;
    }

    // ---- wave (64-lane) + block reduction ----
    #pragma unroll
    for (int off = 32; off > 0; off >>= 1)
        local += __shfl_down(local, off);

    __shared__ float smem[4];
    const int lane = threadIdx.x & 63;
    const int wid  = threadIdx.x >> 6;
    if (lane == 0) smem[wid] = local;
    __syncthreads();
    if (threadIdx.x == 0)
        partials[blockIdx.x] = smem[0] + smem[1] + smem[2] + smem[3];
}

// ---------------- pass 2: deterministic final reduce -------------------------
__global__ __launch_bounds__(256) void surv_final(
    const float* __restrict__ partials, int n,
    float* __restrict__ out, float inv_count)
{
    float local = 0.0f;
    for (int i = threadIdx.x; i < n; i += 256)
        local += partials[i];

    #pragma unroll
    for (int off = 32; off > 0; off >>= 1)
        local += __shfl_down(local, off);

    __shared__ float smem[4];
    const int lane = threadIdx.x & 63;
    const int wid  = threadIdx.x >> 6;
    if (lane == 0) smem[wid] = local;
    __syncthreads();
    if (threadIdx.x == 0)
        out[0] = (smem[0] + smem[1] + smem[2] + smem[3]) * inv_count;
}

extern "C" void kernel_launch(void* const* d_in, const int* in_sizes, int n_in,
                              void* d_out, int out_size, void* d_ws, size_t ws_size,
                              hipStream_t stream)
{
    const float* hazard      = (const float*)d_in[0];
    const int*   event_times = (const int*)d_in[1];
    const int*   censored    = (const int*)d_in[2];
    float*       out         = (float*)d_out;

    const int B = in_sizes[1];              // 262144
    (void)n_in; (void)out_size; (void)ws_size;

    float* partials = (float*)d_ws;

    const int threads = 256;
    const int cols_per_block = threads * CPT;                         // 2048
    const int col_blocks = (B + cols_per_block - 1) / cols_per_block; // 128
    const int nblocks = col_blocks * NCHUNK;                          // 1024

    surv_partial<<<nblocks, threads, 0, stream>>>(hazard, event_times, censored,
                                                  partials, B);
    surv_final<<<1, threads, 0, stream>>>(partials, nblocks, out, 1.0f / (float)B);
}